// Round 2
// baseline (42903.824 us; speedup 1.0000x reference)
//
#include <hip/hip_runtime.h>
#include <hip/hip_cooperative_groups.h>
#include <math.h>

namespace cg = cooperative_groups;

#define BB 64
#define TT 512
#define EE 512
#define UU 1024
#define GG 4096
#define K1 1024
#define K2 2048

// workspace layout (float offsets)
#define OFF_TZ 0u
#define SZ_TZ  (1024u*4096u)            // tz[v][u][4 gates]
#define OFF_P0 (OFF_TZ + SZ_TZ)
#define SZ_P0  (256u*1024u*16u)         // P0[wg][k][j*4+g]
#define OFF_P1 (OFF_P0 + SZ_P0)
#define SZ_P1  (256u*2048u*16u)         // P1[wg][k][j*4+g]
#define OFF_H0 (OFF_P1 + SZ_P1)
#define SZ_H0  (2u*1024u*64u)           // h0T[parity][u][b]
#define OFF_H1 (OFF_H0 + SZ_H0)
#define SZ_H1  (3u*1024u*64u)           // h1T[slot][u][b]

#define LDS_FLOATS (16384u + 16384u + 256u*17u)
#define LDS_BYTES  (LDS_FLOATS * 4u)

// ---------------- pack kernels ----------------
__global__ __launch_bounds__(256) void pack_p0_k(const float* __restrict__ U0,
                                                 float* __restrict__ P0) {
  unsigned t = blockIdx.x * 256u + threadIdx.x;        // < 1024*4096
  unsigned k = t >> 12, col = t & 4095u;
  unsigned g = col >> 10, u = col & 1023u;
  unsigned w = u >> 2, j = u & 3u;
  P0[((w << 10) + k) * 16u + (j << 2) + g] = U0[t];
}

__global__ __launch_bounds__(256) void pack_p1_k(const float* __restrict__ W1,
                                                 const float* __restrict__ U1,
                                                 float* __restrict__ P1) {
  unsigned t = blockIdx.x * 256u + threadIdx.x;        // < 2048*4096
  unsigned k = t >> 12, col = t & 4095u;
  float v = (k < 1024u) ? W1[(k << 12) + col] : U1[((k - 1024u) << 12) + col];
  unsigned g = col >> 10, u = col & 1023u;
  unsigned w = u >> 2, j = u & 3u;
  P1[((w << 11) + k) * 16u + (j << 2) + g] = v;
}

// ---------------- tz = embed @ W0 + b0, stored [v][u][g] ----------------
__global__ __launch_bounds__(256) void tz_gemm_k(const float* __restrict__ embed,
                                                 const float* __restrict__ W0,
                                                 const float* __restrict__ b0,
                                                 float* __restrict__ tz) {
  const int c0 = blockIdx.x << 6;
  const int v0 = blockIdx.y << 6;
  __shared__ float As[32][65];
  __shared__ float Bs[32][65];
  const int tid = threadIdx.x;
  const int tr = tid >> 4, tc = tid & 15;
  float acc[4][4];
#pragma unroll
  for (int r = 0; r < 4; ++r)
#pragma unroll
    for (int c = 0; c < 4; ++c) acc[r][c] = 0.f;

  for (int kc = 0; kc < EE; kc += 32) {
    __syncthreads();
    {
      int kk = tid & 31, vv = tid >> 5;
#pragma unroll
      for (int p = 0; p < 8; ++p)
        As[kk][vv + (p << 3)] = embed[(size_t)(v0 + vv + (p << 3)) * EE + kc + kk];
    }
    {
      int cc = tid & 63, kk = tid >> 6;
#pragma unroll
      for (int p = 0; p < 8; ++p)
        Bs[kk + (p << 2)][cc] = W0[(size_t)(kc + kk + (p << 2)) * GG + c0 + cc];
    }
    __syncthreads();
#pragma unroll 8
    for (int kk = 0; kk < 32; ++kk) {
      float av[4], bv[4];
#pragma unroll
      for (int r = 0; r < 4; ++r) av[r] = As[kk][(tr << 2) + r];
#pragma unroll
      for (int c = 0; c < 4; ++c) bv[c] = Bs[kk][(tc << 2) + c];
#pragma unroll
      for (int r = 0; r < 4; ++r)
#pragma unroll
        for (int c = 0; c < 4; ++c) acc[r][c] = fmaf(av[r], bv[c], acc[r][c]);
    }
  }
#pragma unroll
  for (int r = 0; r < 4; ++r) {
    int v = v0 + (tr << 2) + r;
#pragma unroll
    for (int c = 0; c < 4; ++c) {
      int col = c0 + (tc << 2) + c;
      int g = col >> 10, u = col & 1023;
      tz[(size_t)v * 4096 + (u << 2) + g] = acc[r][c] + b0[col];
    }
  }
}

#define FMA16(A, W0v, W1v, W2v, W3v)                                      \
  do {                                                                    \
    acc[0] = fmaf((A), (W0v).x, acc[0]);  acc[1] = fmaf((A), (W0v).y, acc[1]); \
    acc[2] = fmaf((A), (W0v).z, acc[2]);  acc[3] = fmaf((A), (W0v).w, acc[3]); \
    acc[4] = fmaf((A), (W1v).x, acc[4]);  acc[5] = fmaf((A), (W1v).y, acc[5]); \
    acc[6] = fmaf((A), (W1v).z, acc[6]);  acc[7] = fmaf((A), (W1v).w, acc[7]); \
    acc[8] = fmaf((A), (W2v).x, acc[8]);  acc[9] = fmaf((A), (W2v).y, acc[9]); \
    acc[10] = fmaf((A), (W2v).z, acc[10]); acc[11] = fmaf((A), (W2v).w, acc[11]); \
    acc[12] = fmaf((A), (W3v).x, acc[12]); acc[13] = fmaf((A), (W3v).w * 0.f + (W3v).y, acc[13]); \
    acc[14] = fmaf((A), (W3v).z, acc[14]); acc[15] = fmaf((A), (W3v).w, acc[15]); \
  } while (0)

// NOTE: the W3v.y term above must be exact — rewrite cleanly:
#undef FMA16
#define FMA16(A, W0v, W1v, W2v, W3v)                                      \
  do {                                                                    \
    acc[0]  = fmaf((A), (W0v).x, acc[0]);  acc[1]  = fmaf((A), (W0v).y, acc[1]);  \
    acc[2]  = fmaf((A), (W0v).z, acc[2]);  acc[3]  = fmaf((A), (W0v).w, acc[3]);  \
    acc[4]  = fmaf((A), (W1v).x, acc[4]);  acc[5]  = fmaf((A), (W1v).y, acc[5]);  \
    acc[6]  = fmaf((A), (W1v).z, acc[6]);  acc[7]  = fmaf((A), (W1v).w, acc[7]);  \
    acc[8]  = fmaf((A), (W2v).x, acc[8]);  acc[9]  = fmaf((A), (W2v).y, acc[9]);  \
    acc[10] = fmaf((A), (W2v).z, acc[10]); acc[11] = fmaf((A), (W2v).w, acc[11]); \
    acc[12] = fmaf((A), (W3v).x, acc[12]); acc[13] = fmaf((A), (W3v).y, acc[13]); \
    acc[14] = fmaf((A), (W3v).z, acc[14]); acc[15] = fmaf((A), (W3v).w, acc[15]); \
  } while (0)

// ---------------- persistent cooperative LSTM ----------------
// 256 WGs x 512 thr. WG owns units [wg*4, wg*4+4) of both layers.
// LDS: W0s (P0 slice, 64KB) + W1s (P1 k<1024 slice, 64KB) + zp (17KB, 2-stage reduce).
// Streamed per step: P1 k>=1024 slice (64KB/CU, L2-resident) via deep prefetch.
__global__ __launch_bounds__(512, 2) void lstm_coop_k(const int* __restrict__ tokens,
                                                      const float* __restrict__ tz,
                                                      const float* __restrict__ P0,
                                                      const float* __restrict__ P1,
                                                      const float* __restrict__ b1,
                                                      float* __restrict__ h0T,
                                                      float* __restrict__ h1T,
                                                      float* __restrict__ out) {
  extern __shared__ float lds[];
  float* W0s = lds;              // [1024][16]
  float* W1s = lds + 16384;      // [1024][16] (k = 0..1023 of P1)
  float* zp  = lds + 32768;      // [256][17]

  cg::grid_group grid = cg::this_grid();
  const int tid = threadIdx.x;
  const int wg = blockIdx.x;
  const int lane = tid & 63;               // batch row
  const int wave = tid >> 6;               // keep as VGPR for streamed addressing
  const int wv = __builtin_amdgcn_readfirstlane(wave);
  const int ubase = wg << 2;
  const int j = tid >> 6;                  // unit offset for reducer threads (tid<256)

  const float* __restrict__ P0w = P0 + (size_t)wg * (K1 * 16);
  const float* __restrict__ P1w = P1 + (size_t)wg * (K2 * 16);

  // ---- one-time LDS weight preload ----
  {
    const float4* s0 = (const float4*)P0w;
    const float4* s1 = (const float4*)P1w;          // first 16384 floats = k<1024
    float4* d0 = (float4*)W0s;
    float4* d1 = (float4*)W1s;
#pragma unroll
    for (int t = 0; t < 8; ++t) {
      d0[tid + (t << 9)] = s0[tid + (t << 9)];
      d1[tid + (t << 9)] = s1[tid + (t << 9)];
    }
  }
  __syncthreads();

  float c0 = 0.f, c1 = 0.f;
  float b1v[4] = {0.f, 0.f, 0.f, 0.f};
  if (tid < 256) {
#pragma unroll
    for (int g = 0; g < 4; ++g) b1v[g] = b1[(g << 10) + ubase + j];
  }

  for (int ss = 0; ss <= TT; ++ss) {
    const int wp = ss & 1, rp = wp ^ 1;
    const int s1w = (ss + 2) % 3;
    const int s1r = (ss + 1) % 3;

    // ================= phase A: layer 0, h0(ss) =================
    if (ss < TT) {
      float4 tzv = make_float4(0.f, 0.f, 0.f, 0.f);
      if (tid < 256) {
        int tok = tokens[lane * TT + ss];
        tzv = ((const float4*)tz)[(size_t)tok * 1024 + ubase + j];
      }
      float acc[16];
#pragma unroll
      for (int q = 0; q < 16; ++q) acc[q] = 0.f;
      {
        const int k0 = wv << 7;              // 128 k per wave
        const float* __restrict__ aa = h0T + rp * (UU * BB) + k0 * BB + lane;
        const float* __restrict__ wl = W0s + (k0 << 4);
#pragma unroll 4
        for (int kk = 0; kk < 128; ++kk) {
          float a = aa[kk * BB];
          const float4* w4 = (const float4*)(wl + (kk << 4));
          float4 w0v = w4[0], w1v = w4[1], w2v = w4[2], w3v = w4[3];
          FMA16(a, w0v, w1v, w2v, w3v);
        }
      }
      // two-stage cross-wave reduce
      if (tid >= 256) {
#pragma unroll
        for (int q = 0; q < 16; ++q) zp[(tid - 256) * 17 + q] = acc[q];
      }
      __syncthreads();
      if (tid < 256) {
#pragma unroll
        for (int q = 0; q < 16; ++q) {
          acc[q] += zp[tid * 17 + q];
          zp[tid * 17 + q] = acc[q];
        }
      }
      __syncthreads();
      if (tid < 256) {
        float z[4];
#pragma unroll
        for (int g = 0; g < 4; ++g) {
          float s = ((const float*)&tzv)[g];
#pragma unroll
          for (int w8 = 0; w8 < 4; ++w8) s += zp[(w8 * 64 + lane) * 17 + (j << 2) + g];
          z[g] = s;
        }
        float iG = 1.f / (1.f + expf(-z[0]));
        float fG = 1.f / (1.f + expf(-z[1]));
        float gG = tanhf(z[2]);
        float oG = 1.f / (1.f + expf(-z[3]));
        c0 = fG * c0 + iG * gG;
        float h = oG * tanhf(c0);
        h0T[wp * (UU * BB) + (ubase + j) * BB + lane] = h;
      }
    }

    // ================= phase B: layer 1, h1(ss-1) =================
    if (ss >= 1) {
      float acc[16];
#pragma unroll
      for (int q = 0; q < 16; ++q) acc[q] = 0.f;
      if (wv < 4) {
        // W1 part, k in [wv*256, wv*256+256): weights LDS-resident
        const int k0 = wv << 8;
        const float* __restrict__ aa = h0T + rp * (UU * BB) + k0 * BB + lane;
        const float* __restrict__ wl = W1s + (k0 << 4);
#pragma unroll 4
        for (int kk = 0; kk < 256; ++kk) {
          float a = aa[kk * BB];
          const float4* w4 = (const float4*)(wl + (kk << 4));
          float4 w0v = w4[0], w1v = w4[1], w2v = w4[2], w3v = w4[3];
          FMA16(a, w0v, w1v, w2v, w3v);
        }
      } else {
        // U1 part, k in [1024 + k0v, +256): streamed from global (L2-resident),
        // explicit double-buffered 4-kk-group prefetch. `wave` is VGPR -> VMEM loads.
        const int k0v = (wave - 4) << 8;
        const float* __restrict__ aa = h1T + s1r * (UU * BB) + k0v * BB + lane;
        const float4* __restrict__ wp4 = (const float4*)P1w + ((size_t)(K1 + k0v) << 2);
        float4 bufA[16], bufB[16];
#pragma unroll
        for (int r = 0; r < 16; ++r) bufA[r] = wp4[r];
        for (int g2 = 0; g2 < 64; g2 += 2) {
#pragma unroll
          for (int r = 0; r < 16; ++r) bufB[r] = wp4[(g2 + 1) * 16 + r];
#pragma unroll
          for (int i = 0; i < 4; ++i) {
            float a = aa[(g2 * 4 + i) * BB];
            FMA16(a, bufA[i * 4 + 0], bufA[i * 4 + 1], bufA[i * 4 + 2], bufA[i * 4 + 3]);
          }
          if (g2 + 2 < 64) {
#pragma unroll
            for (int r = 0; r < 16; ++r) bufA[r] = wp4[(g2 + 2) * 16 + r];
          }
#pragma unroll
          for (int i = 0; i < 4; ++i) {
            float a = aa[((g2 + 1) * 4 + i) * BB];
            FMA16(a, bufB[i * 4 + 0], bufB[i * 4 + 1], bufB[i * 4 + 2], bufB[i * 4 + 3]);
          }
        }
      }
      __syncthreads();                       // phase-A zp readers done before reuse
      if (tid >= 256) {
#pragma unroll
        for (int q = 0; q < 16; ++q) zp[(tid - 256) * 17 + q] = acc[q];
      }
      __syncthreads();
      if (tid < 256) {
#pragma unroll
        for (int q = 0; q < 16; ++q) {
          acc[q] += zp[tid * 17 + q];
          zp[tid * 17 + q] = acc[q];
        }
      }
      __syncthreads();
      if (tid < 256) {
        float z[4];
#pragma unroll
        for (int g = 0; g < 4; ++g) {
          float s = b1v[g];
#pragma unroll
          for (int w8 = 0; w8 < 4; ++w8) s += zp[(w8 * 64 + lane) * 17 + (j << 2) + g];
          z[g] = s;
        }
        float iG = 1.f / (1.f + expf(-z[0]));
        float fG = 1.f / (1.f + expf(-z[1]));
        float gG = tanhf(z[2]);
        float oG = 1.f / (1.f + expf(-z[3]));
        c1 = fG * c1 + iG * gG;
        float h = oG * tanhf(c1);
        h1T[s1w * (UU * BB) + (ubase + j) * BB + lane] = h;
        out[(size_t)lane * (TT * UU) + (size_t)(ss - 1) * UU + ubase + j] = h;
      }
    }
    grid.sync();
  }
}

// ---------------- host ----------------
extern "C" void kernel_launch(void* const* d_in, const int* in_sizes, int n_in,
                              void* d_out, int out_size, void* d_ws, size_t ws_size,
                              hipStream_t stream) {
  const int*   tokens = (const int*)d_in[0];
  const float* embed  = (const float*)d_in[1];
  const float* W0     = (const float*)d_in[2];
  const float* U0     = (const float*)d_in[3];
  const float* b0     = (const float*)d_in[4];
  const float* W1     = (const float*)d_in[5];
  const float* U1     = (const float*)d_in[6];
  const float* b1     = (const float*)d_in[7];
  float* ws  = (float*)d_ws;
  float* tz  = ws + OFF_TZ;
  float* P0  = ws + OFF_P0;
  float* P1  = ws + OFF_P1;
  float* h0T = ws + OFF_H0;
  float* h1T = ws + OFF_H1;
  float* out = (float*)d_out;

  hipFuncSetAttribute((const void*)lstm_coop_k,
                      hipFuncAttributeMaxDynamicSharedMemorySize, LDS_BYTES);

  hipMemsetAsync(h0T, 0, (SZ_H0 + SZ_H1) * sizeof(float), stream);

  pack_p0_k<<<16384, 256, 0, stream>>>(U0, P0);
  pack_p1_k<<<32768, 256, 0, stream>>>(W1, U1, P1);
  tz_gemm_k<<<dim3(64, 16), 256, 0, stream>>>(embed, W0, b0, tz);

  void* args[] = {(void*)&tokens, (void*)&tz, (void*)&P0, (void*)&P1,
                  (void*)&b1, (void*)&h0T, (void*)&h1T, (void*)&out};
  hipLaunchCooperativeKernel((void*)lstm_coop_k, dim3(256), dim3(512), args,
                             LDS_BYTES, stream);
}

// Round 3
// 23312.378 us; speedup vs baseline: 1.8404x; 1.8404x over previous
//
#include <hip/hip_runtime.h>
#include <hip/hip_cooperative_groups.h>
#include <math.h>

typedef __attribute__((ext_vector_type(8))) short s8v;   // 8 bf16 (A/B frag)
typedef __attribute__((ext_vector_type(4))) float f4v;   // 4 fp32 (C/D frag)

#define TT 512
#define UU 1024
#define HSE (64*1024)            // elems per h plane [64 b][1024 u]

// ---- ws byte offsets ----
#define B_TZ   0ull              // fp32 tz[v][u][g]  16 MB
#define B_A0H  16777216ull       // A0 hi frags  8 MB
#define B_A0L  25165824ull       // A0 lo frags  8 MB
#define B_A1H  33554432ull       // A1 hi frags 16 MB
#define B_A1L  50331648ull       // A1 lo frags 16 MB
#define B_H0H  67108864ull       // h0 hi, 2 parities
#define B_H0L  (B_H0H + 2ull*HSE*2ull)
#define B_H1H  (B_H0L + 2ull*HSE*2ull)
#define B_H1L  (B_H1H + 3ull*HSE*2ull)
#define B_BAR  (B_H1L + 3ull*HSE*2ull)   // 2 x u32 barrier state

__device__ __forceinline__ unsigned short f2bf(float x) {
  unsigned u = __float_as_uint(x);
  unsigned r = (u + 0x7fffu + ((u >> 16) & 1u)) >> 16;
  return (unsigned short)r;
}

#define MFMA(a, b, c) __builtin_amdgcn_mfma_f32_16x16x32_bf16((a), (b), (c), 0, 0, 0)

// ---------------- A-fragment pack kernels ----------------
// lane l holds A[m = l&15][k = (l>>4)*8 + j], m=col=4*unit_j+gate.
__global__ __launch_bounds__(256) void pack_a0_k(const float* __restrict__ U0,
                                                 unsigned short* __restrict__ A0h,
                                                 unsigned short* __restrict__ A0l,
                                                 unsigned* __restrict__ bar) {
  unsigned e = blockIdx.x * 256u + threadIdx.x;          // < 4M
  if (e < 2) bar[e] = 0u;                                // re-init barrier each launch
  unsigned j = e & 7u, lane = (e >> 3) & 63u, ch = (e >> 9) & 3u;
  unsigned wv = (e >> 11) & 7u, wg = e >> 14;
  unsigned quad = lane >> 4, col = lane & 15u;
  unsigned k = wv * 128u + ch * 32u + quad * 8u + j;
  unsigned c = (col & 3u) * 1024u + wg * 4u + (col >> 2);
  float x = U0[(size_t)k * 4096u + c];
  unsigned short h = f2bf(x);
  A0h[e] = h;
  A0l[e] = f2bf(x - __uint_as_float(((unsigned)h) << 16));
}

__global__ __launch_bounds__(256) void pack_a1_k(const float* __restrict__ W1,
                                                 const float* __restrict__ U1,
                                                 unsigned short* __restrict__ A1h,
                                                 unsigned short* __restrict__ A1l) {
  unsigned e = blockIdx.x * 256u + threadIdx.x;          // < 8M
  unsigned j = e & 7u, lane = (e >> 3) & 63u, ch = (e >> 9) & 7u;
  unsigned wv = (e >> 12) & 7u, wg = e >> 15;
  unsigned quad = lane >> 4, col = lane & 15u;
  unsigned k = wv * 256u + ch * 32u + quad * 8u + j;
  unsigned c = (col & 3u) * 1024u + wg * 4u + (col >> 2);
  float x = (k < 1024u) ? W1[(size_t)k * 4096u + c] : U1[(size_t)(k - 1024u) * 4096u + c];
  unsigned short h = f2bf(x);
  A1h[e] = h;
  A1l[e] = f2bf(x - __uint_as_float(((unsigned)h) << 16));
}

// ---------------- tz = embed @ W0 + b0, stored [v][u][g] ----------------
__global__ __launch_bounds__(256) void tz_gemm_k(const float* __restrict__ embed,
                                                 const float* __restrict__ W0,
                                                 const float* __restrict__ b0,
                                                 float* __restrict__ tz) {
  const int c0 = blockIdx.x << 6;
  const int v0 = blockIdx.y << 6;
  __shared__ float As[32][65];
  __shared__ float Bs[32][65];
  const int tid = threadIdx.x;
  const int tr = tid >> 4, tc = tid & 15;
  float acc[4][4];
#pragma unroll
  for (int r = 0; r < 4; ++r)
#pragma unroll
    for (int c = 0; c < 4; ++c) acc[r][c] = 0.f;

  for (int kc = 0; kc < 512; kc += 32) {
    __syncthreads();
    {
      int kk = tid & 31, vv = tid >> 5;
#pragma unroll
      for (int p = 0; p < 8; ++p)
        As[kk][vv + (p << 3)] = embed[(size_t)(v0 + vv + (p << 3)) * 512 + kc + kk];
    }
    {
      int cc = tid & 63, kk = tid >> 6;
#pragma unroll
      for (int p = 0; p < 8; ++p)
        Bs[kk + (p << 2)][cc] = W0[(size_t)(kc + kk + (p << 2)) * 4096 + c0 + cc];
    }
    __syncthreads();
#pragma unroll 8
    for (int kk = 0; kk < 32; ++kk) {
      float av[4], bv[4];
#pragma unroll
      for (int r = 0; r < 4; ++r) av[r] = As[kk][(tr << 2) + r];
#pragma unroll
      for (int c = 0; c < 4; ++c) bv[c] = Bs[kk][(tc << 2) + c];
#pragma unroll
      for (int r = 0; r < 4; ++r)
#pragma unroll
        for (int c = 0; c < 4; ++c) acc[r][c] = fmaf(av[r], bv[c], acc[r][c]);
    }
  }
#pragma unroll
  for (int r = 0; r < 4; ++r) {
    int v = v0 + (tr << 2) + r;
#pragma unroll
    for (int c = 0; c < 4; ++c) {
      int col = c0 + (tc << 2) + c;
      int g = col >> 10, u = col & 1023;
      tz[(size_t)v * 4096 + (u << 2) + g] = acc[r][c] + b0[col];
    }
  }
}

// ---------------- custom grid barrier (monotonic, relaxed polls) ----------------
__device__ __forceinline__ void grid_bar(unsigned* cnt, unsigned* gen, unsigned round) {
  __syncthreads();
  if (threadIdx.x == 0) {
    __builtin_amdgcn_fence(__ATOMIC_RELEASE, "agent");
    unsigned prev = __hip_atomic_fetch_add(cnt, 1u, __ATOMIC_RELAXED, __HIP_MEMORY_SCOPE_AGENT);
    if (prev == round * 256u + 255u) {
      __hip_atomic_store(gen, round + 1u, __ATOMIC_RELAXED, __HIP_MEMORY_SCOPE_AGENT);
    } else {
      while (__hip_atomic_load(gen, __ATOMIC_RELAXED, __HIP_MEMORY_SCOPE_AGENT) <= round)
        __builtin_amdgcn_s_sleep(2);
    }
    __builtin_amdgcn_fence(__ATOMIC_ACQUIRE, "agent");
  }
  __syncthreads();
}

// ---------------- persistent MFMA LSTM ----------------
// 256 WGs x 512 thr. WG owns 16 gate-cols (4 units) of both layers.
// Weights: register-stationary A-frags (hi+lo bf16). Activations: bf16 hi/lo
// [b][unit] in global; B-frags are 16B/lane loads. z reduce via 32KB LDS.
__global__ __launch_bounds__(512, 2) void lstm_coop_k(const int* __restrict__ tokens,
                                                      const float* __restrict__ tz,
                                                      const unsigned short* __restrict__ A0h,
                                                      const unsigned short* __restrict__ A0l,
                                                      const unsigned short* __restrict__ A1h,
                                                      const unsigned short* __restrict__ A1l,
                                                      const float* __restrict__ b1,
                                                      unsigned short* __restrict__ h0h,
                                                      unsigned short* __restrict__ h0l,
                                                      unsigned short* __restrict__ h1h,
                                                      unsigned short* __restrict__ h1l,
                                                      float* __restrict__ out,
                                                      unsigned* __restrict__ bar) {
  __shared__ f4v zp4[2048];                 // [wave][b][quad] = 32 KB

  const int tid = threadIdx.x;
  const int wg = blockIdx.x;
  const int lane = tid & 63;
  const int wv = __builtin_amdgcn_readfirstlane(tid >> 6);
  const int quad = lane >> 4, n = lane & 15;
  const int j = tid >> 6;                   // unit offset for update threads (tid<256)
  unsigned* cnt = bar;
  unsigned* gen = bar + 1;

  // ---- stationary weight fragments ----
  s8v a0h[4], a0l[4], a1h[8], a1l[8];
  {
    const s8v* p0h = (const s8v*)A0h + ((wg * 8 + wv) * 4) * 64 + lane;
    const s8v* p0l = (const s8v*)A0l + ((wg * 8 + wv) * 4) * 64 + lane;
#pragma unroll
    for (int ch = 0; ch < 4; ++ch) { a0h[ch] = p0h[ch * 64]; a0l[ch] = p0l[ch * 64]; }
    const s8v* p1h = (const s8v*)A1h + ((wg * 8 + wv) * 8) * 64 + lane;
    const s8v* p1l = (const s8v*)A1l + ((wg * 8 + wv) * 8) * 64 + lane;
#pragma unroll
    for (int ch = 0; ch < 8; ++ch) { a1h[ch] = p1h[ch * 64]; a1l[ch] = p1l[ch * 64]; }
  }

  float c0 = 0.f, c1 = 0.f;
  f4v b1v = {0.f, 0.f, 0.f, 0.f};
  if (tid < 256) {
    b1v.x = b1[0 * 1024 + wg * 4 + j];
    b1v.y = b1[1 * 1024 + wg * 4 + j];
    b1v.z = b1[2 * 1024 + wg * 4 + j];
    b1v.w = b1[3 * 1024 + wg * 4 + j];
  }

  for (int ss = 0; ss <= TT; ++ss) {
    const int wp = ss & 1, rp = wp ^ 1;
    const int s1w = (ss + 2) % 3;            // slot for h1(ss-1)
    const int s1r = (ss + 1) % 3;            // slot of h1(ss-2)

    // ================= phase A: layer 0, h0(ss) =================
    if (ss < TT) {
      f4v tzv = {0.f, 0.f, 0.f, 0.f};
      if (tid < 256) {
        int tok = tokens[lane * TT + ss];
        tzv = ((const f4v*)tz)[(size_t)tok * 1024 + wg * 4 + j];
      }
      f4v acc[4];
#pragma unroll
      for (int t = 0; t < 4; ++t) acc[t] = (f4v){0.f, 0.f, 0.f, 0.f};
      {
        const unsigned short* bhB = h0h + rp * HSE;
        const unsigned short* blB = h0l + rp * HSE;
        const int co = wv * 128 + quad * 8;
#pragma unroll
        for (int ch = 0; ch < 4; ++ch) {
          s8v bh[4], bl[4];
#pragma unroll
          for (int t = 0; t < 4; ++t) {
            int off = (t * 16 + n) * 1024 + co + ch * 32;
            bh[t] = *(const s8v*)(bhB + off);
            bl[t] = *(const s8v*)(blB + off);
          }
#pragma unroll
          for (int t = 0; t < 4; ++t) {
            acc[t] = MFMA(a0h[ch], bh[t], acc[t]);
            acc[t] = MFMA(a0l[ch], bh[t], acc[t]);
            acc[t] = MFMA(a0h[ch], bl[t], acc[t]);
          }
        }
      }
#pragma unroll
      for (int t = 0; t < 4; ++t) zp4[(wv * 64 + t * 16 + n) * 4 + quad] = acc[t];
      __syncthreads();
      if (tid < 256) {
        f4v s = tzv;
#pragma unroll
        for (int w = 0; w < 8; ++w) s += zp4[(w * 64 + lane) * 4 + j];
        float iG = 1.f / (1.f + expf(-s.x));
        float fG = 1.f / (1.f + expf(-s.y));
        float gG = tanhf(s.z);
        float oG = 1.f / (1.f + expf(-s.w));
        c0 = fG * c0 + iG * gG;
        float h = oG * tanhf(c0);
        unsigned short hb = f2bf(h);
        int ho = wp * HSE + lane * 1024 + wg * 4 + j;
        h0h[ho] = hb;
        h0l[ho] = f2bf(h - __uint_as_float(((unsigned)hb) << 16));
      }
    }

    // ================= phase B: layer 1, h1(ss-1) =================
    if (ss >= 1) {
      f4v acc[4];
#pragma unroll
      for (int t = 0; t < 4; ++t) acc[t] = (f4v){0.f, 0.f, 0.f, 0.f};
      {
        const unsigned short* bhB;
        const unsigned short* blB;
        int co;
        if (wv < 4) {                        // W1 part: x = h0(ss-1)
          bhB = h0h + rp * HSE; blB = h0l + rp * HSE; co = wv * 256 + quad * 8;
        } else {                             // U1 part: h1(ss-2)
          bhB = h1h + s1r * HSE; blB = h1l + s1r * HSE; co = (wv - 4) * 256 + quad * 8;
        }
#pragma unroll
        for (int ch = 0; ch < 8; ++ch) {
          s8v bh[4], bl[4];
#pragma unroll
          for (int t = 0; t < 4; ++t) {
            int off = (t * 16 + n) * 1024 + co + ch * 32;
            bh[t] = *(const s8v*)(bhB + off);
            bl[t] = *(const s8v*)(blB + off);
          }
#pragma unroll
          for (int t = 0; t < 4; ++t) {
            acc[t] = MFMA(a1h[ch], bh[t], acc[t]);
            acc[t] = MFMA(a1l[ch], bh[t], acc[t]);
            acc[t] = MFMA(a1h[ch], bl[t], acc[t]);
          }
        }
      }
      __syncthreads();                       // phase-A zp readers done before reuse
#pragma unroll
      for (int t = 0; t < 4; ++t) zp4[(wv * 64 + t * 16 + n) * 4 + quad] = acc[t];
      __syncthreads();
      if (tid < 256) {
        f4v s = b1v;
#pragma unroll
        for (int w = 0; w < 8; ++w) s += zp4[(w * 64 + lane) * 4 + j];
        float iG = 1.f / (1.f + expf(-s.x));
        float fG = 1.f / (1.f + expf(-s.y));
        float gG = tanhf(s.z);
        float oG = 1.f / (1.f + expf(-s.w));
        c1 = fG * c1 + iG * gG;
        float h = oG * tanhf(c1);
        unsigned short hb = f2bf(h);
        int ho = s1w * HSE + lane * 1024 + wg * 4 + j;
        h1h[ho] = hb;
        h1l[ho] = f2bf(h - __uint_as_float(((unsigned)hb) << 16));
        out[(size_t)lane * (TT * UU) + (size_t)(ss - 1) * UU + wg * 4 + j] = h;
      }
    }
    grid_bar(cnt, gen, (unsigned)ss);
  }
}

// ---------------- host ----------------
extern "C" void kernel_launch(void* const* d_in, const int* in_sizes, int n_in,
                              void* d_out, int out_size, void* d_ws, size_t ws_size,
                              hipStream_t stream) {
  const int*   tokens = (const int*)d_in[0];
  const float* embed  = (const float*)d_in[1];
  const float* W0     = (const float*)d_in[2];
  const float* U0     = (const float*)d_in[3];
  const float* b0     = (const float*)d_in[4];
  const float* W1     = (const float*)d_in[5];
  const float* U1     = (const float*)d_in[6];
  const float* b1     = (const float*)d_in[7];
  char* ws = (char*)d_ws;
  float*          tz  = (float*)(ws + B_TZ);
  unsigned short* A0h = (unsigned short*)(ws + B_A0H);
  unsigned short* A0l = (unsigned short*)(ws + B_A0L);
  unsigned short* A1h = (unsigned short*)(ws + B_A1H);
  unsigned short* A1l = (unsigned short*)(ws + B_A1L);
  unsigned short* h0h = (unsigned short*)(ws + B_H0H);
  unsigned short* h0l = (unsigned short*)(ws + B_H0L);
  unsigned short* h1h = (unsigned short*)(ws + B_H1H);
  unsigned short* h1l = (unsigned short*)(ws + B_H1L);
  unsigned*       bar = (unsigned*)(ws + B_BAR);
  float* out = (float*)d_out;

  // zero h state + barrier (ws poisoned 0xAA before every call)
  hipMemsetAsync(ws + B_H0H, 0, (size_t)(B_BAR + 8 - B_H0H), stream);

  pack_a0_k<<<16384, 256, 0, stream>>>(U0, A0h, A0l, bar);
  pack_a1_k<<<32768, 256, 0, stream>>>(W1, U1, A1h, A1l);
  tz_gemm_k<<<dim3(64, 16), 256, 0, stream>>>(embed, W0, b0, tz);

  void* args[] = {(void*)&tokens, (void*)&tz, (void*)&A0h, (void*)&A0l,
                  (void*)&A1h, (void*)&A1l, (void*)&b1, (void*)&h0h, (void*)&h0l,
                  (void*)&h1h, (void*)&h1l, (void*)&out, (void*)&bar};
  hipLaunchCooperativeKernel((void*)lstm_coop_k, dim3(256), dim3(512), args, 0, stream);
}

// Round 4
// 21273.009 us; speedup vs baseline: 2.0168x; 1.0959x over previous
//
#include <hip/hip_runtime.h>
#include <math.h>

typedef __attribute__((ext_vector_type(8))) short s8v;   // 8 bf16 (A/B frag)
typedef __attribute__((ext_vector_type(4))) float f4v;   // 4 fp32 (C/D frag)
typedef unsigned long long u64;

#define TT 512
#define UU 1024
#define HSZ 65536u               // u32 per h slot: [64 b][1024 u] packed hi|lo

// ---- ws byte offsets ----
#define B_TZ   0ull              // fp32 tz[v][u][g]  16 MB
#define B_A0H  16777216ull       // A0 hi frags  8 MB
#define B_A0L  25165824ull
#define B_A1H  33554432ull       // A1 hi frags 16 MB
#define B_A1L  50331648ull
#define B_H0   67108864ull       // h0 packed u32, 3 slots (768 KB)
#define B_H1   (B_H0 + 3ull*HSZ*4ull)
#define B_BAR  (B_H1 + 3ull*HSZ*4ull)   // barrier block (4 KB)

__device__ __forceinline__ unsigned short f2bf(float x) {
  unsigned u = __float_as_uint(x);
  return (unsigned short)((u + 0x7fffu + ((u >> 16) & 1u)) >> 16);
}

#define MFMA(a, b, c) __builtin_amdgcn_mfma_f32_16x16x32_bf16((a), (b), (c), 0, 0, 0)

__device__ __forceinline__ u64 ldsc(const u64* p) {
  return __hip_atomic_load(p, __ATOMIC_RELAXED, __HIP_MEMORY_SCOPE_AGENT);
}
__device__ __forceinline__ void stsc(u64* p, u64 v) {
  __hip_atomic_store(p, v, __ATOMIC_RELAXED, __HIP_MEMORY_SCOPE_AGENT);
}

// unpack 4 u64 (8 units, each u32 = hi16<<16 | lo16) into hi/lo bf16 frags
__device__ __forceinline__ void unpack8(const u64* q, s8v& bh, s8v& bl) {
  union { uint4 u; s8v s; } H, L;
  H.u.x = __builtin_amdgcn_perm((unsigned)(q[0] >> 32), (unsigned)q[0], 0x07060302u);
  H.u.y = __builtin_amdgcn_perm((unsigned)(q[1] >> 32), (unsigned)q[1], 0x07060302u);
  H.u.z = __builtin_amdgcn_perm((unsigned)(q[2] >> 32), (unsigned)q[2], 0x07060302u);
  H.u.w = __builtin_amdgcn_perm((unsigned)(q[3] >> 32), (unsigned)q[3], 0x07060302u);
  L.u.x = __builtin_amdgcn_perm((unsigned)(q[0] >> 32), (unsigned)q[0], 0x05040100u);
  L.u.y = __builtin_amdgcn_perm((unsigned)(q[1] >> 32), (unsigned)q[1], 0x05040100u);
  L.u.z = __builtin_amdgcn_perm((unsigned)(q[2] >> 32), (unsigned)q[2], 0x05040100u);
  L.u.w = __builtin_amdgcn_perm((unsigned)(q[3] >> 32), (unsigned)q[3], 0x05040100u);
  bh = H.s; bl = L.s;
}

// ---------------- A-fragment pack kernels ----------------
__global__ __launch_bounds__(256) void pack_a0_k(const float* __restrict__ U0,
                                                 unsigned short* __restrict__ A0h,
                                                 unsigned short* __restrict__ A0l) {
  unsigned e = blockIdx.x * 256u + threadIdx.x;          // < 4M
  unsigned j = e & 7u, lane = (e >> 3) & 63u, ch = (e >> 9) & 3u;
  unsigned wv = (e >> 11) & 7u, wg = e >> 14;
  unsigned quad = lane >> 4, col = lane & 15u;
  unsigned k = wv * 128u + ch * 32u + quad * 8u + j;
  unsigned c = (col & 3u) * 1024u + wg * 4u + (col >> 2);
  float x = U0[(size_t)k * 4096u + c];
  unsigned short h = f2bf(x);
  A0h[e] = h;
  A0l[e] = f2bf(x - __uint_as_float(((unsigned)h) << 16));
}

// A1: ch<4 = W1 rows k=wv*128+ch*32+..., ch>=4 = U1 rows k=wv*128+(ch-4)*32+...
__global__ __launch_bounds__(256) void pack_a1_k(const float* __restrict__ W1,
                                                 const float* __restrict__ U1,
                                                 unsigned short* __restrict__ A1h,
                                                 unsigned short* __restrict__ A1l) {
  unsigned e = blockIdx.x * 256u + threadIdx.x;          // < 8M
  unsigned j = e & 7u, lane = (e >> 3) & 63u, ch = (e >> 9) & 7u;
  unsigned wv = (e >> 12) & 7u, wg = e >> 15;
  unsigned quad = lane >> 4, col = lane & 15u;
  unsigned k = wv * 128u + (ch & 3u) * 32u + quad * 8u + j;
  unsigned c = (col & 3u) * 1024u + wg * 4u + (col >> 2);
  float x = (ch < 4u) ? W1[(size_t)k * 4096u + c] : U1[(size_t)k * 4096u + c];
  unsigned short h = f2bf(x);
  A1h[e] = h;
  A1l[e] = f2bf(x - __uint_as_float(((unsigned)h) << 16));
}

// ---------------- tz = embed @ W0 + b0, stored [v][u][g] ----------------
__global__ __launch_bounds__(256) void tz_gemm_k(const float* __restrict__ embed,
                                                 const float* __restrict__ W0,
                                                 const float* __restrict__ b0,
                                                 float* __restrict__ tz) {
  const int c0 = blockIdx.x << 6;
  const int v0 = blockIdx.y << 6;
  __shared__ float As[32][65];
  __shared__ float Bs[32][65];
  const int tid = threadIdx.x;
  const int tr = tid >> 4, tc = tid & 15;
  float acc[4][4];
#pragma unroll
  for (int r = 0; r < 4; ++r)
#pragma unroll
    for (int c = 0; c < 4; ++c) acc[r][c] = 0.f;

  for (int kc = 0; kc < 512; kc += 32) {
    __syncthreads();
    {
      int kk = tid & 31, vv = tid >> 5;
#pragma unroll
      for (int p = 0; p < 8; ++p)
        As[kk][vv + (p << 3)] = embed[(size_t)(v0 + vv + (p << 3)) * 512 + kc + kk];
    }
    {
      int cc = tid & 63, kk = tid >> 6;
#pragma unroll
      for (int p = 0; p < 8; ++p)
        Bs[kk + (p << 2)][cc] = W0[(size_t)(kc + kk + (p << 2)) * 4096 + c0 + cc];
    }
    __syncthreads();
#pragma unroll 8
    for (int kk = 0; kk < 32; ++kk) {
      float av[4], bv[4];
#pragma unroll
      for (int r = 0; r < 4; ++r) av[r] = As[kk][(tr << 2) + r];
#pragma unroll
      for (int c = 0; c < 4; ++c) bv[c] = Bs[kk][(tc << 2) + c];
#pragma unroll
      for (int r = 0; r < 4; ++r)
#pragma unroll
        for (int c = 0; c < 4; ++c) acc[r][c] = fmaf(av[r], bv[c], acc[r][c]);
    }
  }
#pragma unroll
  for (int r = 0; r < 4; ++r) {
    int v = v0 + (tr << 2) + r;
#pragma unroll
    for (int c = 0; c < 4; ++c) {
      int col = c0 + (tc << 2) + c;
      int g = col >> 10, u = col & 1023;
      tz[(size_t)v * 4096 + (u << 2) + g] = acc[r][c] + b0[col];
    }
  }
}

// ---------------- hierarchical barrier primitives ----------------
__device__ __forceinline__ void arrive(unsigned* xc, unsigned* gc, unsigned* gen, int grp) {
  unsigned old = __hip_atomic_fetch_add(xc + grp * 32, 1u, __ATOMIC_RELAXED,
                                        __HIP_MEMORY_SCOPE_AGENT);
  if ((old & 31u) == 31u) {
    unsigned o2 = __hip_atomic_fetch_add(gc, 1u, __ATOMIC_RELAXED, __HIP_MEMORY_SCOPE_AGENT);
    if ((o2 & 7u) == 7u)
      __hip_atomic_store(gen, (o2 >> 3) + 1u, __ATOMIC_RELAXED, __HIP_MEMORY_SCOPE_AGENT);
  }
}
__device__ __forceinline__ void waitgen(unsigned* gen, unsigned target) {
  while (__hip_atomic_load(gen, __ATOMIC_RELAXED, __HIP_MEMORY_SCOPE_AGENT) < target)
    __builtin_amdgcn_s_sleep(1);
}

// ---------------- persistent MFMA LSTM ----------------
// 256 WGs x 512 thr (1/CU). WG owns 4 units of both layers; weights register-
// stationary (hi+lo bf16). h packed u32(hi|lo) in MALL-coherent (sc0sc1) space.
// Merged h0 pass: U0 and W1 products share one B-frag load.
__global__ __launch_bounds__(512) void lstm_coop_k(const int* __restrict__ tokens,
                                                   const float* __restrict__ tz,
                                                   const unsigned short* __restrict__ A0h,
                                                   const unsigned short* __restrict__ A0l,
                                                   const unsigned short* __restrict__ A1h,
                                                   const unsigned short* __restrict__ A1l,
                                                   const float* __restrict__ b1,
                                                   unsigned* __restrict__ h0w,
                                                   unsigned* __restrict__ h1w,
                                                   float* __restrict__ out,
                                                   unsigned* __restrict__ bar) {
  __shared__ float zpf[4 * 2080];           // [gate][unit*520 + wave*64 + batch]
  __shared__ unsigned hx[64 * 5];           // h transpose staging [batch][unit(+pad)]

  const int tid = threadIdx.x;
  const int wg = blockIdx.x;
  const int lane = tid & 63;
  const int wv = __builtin_amdgcn_readfirstlane(tid >> 6);
  const int quad = lane >> 4, n = lane & 15;
  const int j = tid >> 6;                   // unit idx for updater threads (tid<256)
  const int grp = wg & 7;
  const bool bt = (tid == 448);             // barrier thread (wave 7 lane 0)

  unsigned* xcA = bar;        unsigned* xcB = bar + 256;
  unsigned* gcA = bar + 512;  unsigned* gcB = bar + 544;
  unsigned* genA = bar + 576; unsigned* genB = bar + 608;

  // ---- stationary weight fragments ----
  s8v a0h[4], a0l[4], a1h[8], a1l[8];
  {
    const s8v* p0h = (const s8v*)A0h + ((wg * 8 + wv) * 4) * 64 + lane;
    const s8v* p0l = (const s8v*)A0l + ((wg * 8 + wv) * 4) * 64 + lane;
#pragma unroll
    for (int ch = 0; ch < 4; ++ch) { a0h[ch] = p0h[ch * 64]; a0l[ch] = p0l[ch * 64]; }
    const s8v* p1h = (const s8v*)A1h + ((wg * 8 + wv) * 8) * 64 + lane;
    const s8v* p1l = (const s8v*)A1l + ((wg * 8 + wv) * 8) * 64 + lane;
#pragma unroll
    for (int ch = 0; ch < 8; ++ch) { a1h[ch] = p1h[ch * 64]; a1l[ch] = p1l[ch * 64]; }
  }

  float c0 = 0.f, c1 = 0.f, hout = 0.f;
  f4v b1v = {0.f, 0.f, 0.f, 0.f};
  if (tid < 256) {
    b1v.x = b1[0 * 1024 + wg * 4 + j];
    b1v.y = b1[1 * 1024 + wg * 4 + j];
    b1v.z = b1[2 * 1024 + wg * 4 + j];
    b1v.w = b1[3 * 1024 + wg * 4 + j];
  }

  const int co = (wv << 7) + (quad << 3);   // this wave's 128-k slice base

  for (int ss = 0; ss <= TT; ++ss) {
    const int s0w = ss % 3, s0r = (ss + 2) % 3;         // h0 slots
    const int s1wr = (ss + 2) % 3, s1r = (ss + 1) % 3;  // h1 slots

    // ---- wait_A: h0(ss-1) stores complete grid-wide ----
    if (bt) waitgen(genA, (unsigned)ss);
    __syncthreads();

    // ======== h0 pass: acc0 = U0·h0(ss-1), acc1 = W1·h0(ss-1) ========
    f4v tzv = {0.f, 0.f, 0.f, 0.f};
    if (ss < TT && tid < 256) {
      int tok = tokens[lane * TT + ss];
      tzv = ((const f4v*)tz)[(size_t)tok * 1024 + (wg << 2) + j];
    }
    f4v acc0[4], acc1[4];
#pragma unroll
    for (int t = 0; t < 4; ++t) { acc0[t] = (f4v){0,0,0,0}; acc1[t] = (f4v){0,0,0,0}; }
    {
      const unsigned* hb = h0w + s0r * HSZ;
#pragma unroll
      for (int ch = 0; ch < 4; ++ch) {
        u64 q[4][4];
#pragma unroll
        for (int t = 0; t < 4; ++t) {
          const u64* p = (const u64*)(hb + ((t * 16 + n) << 10) + co + (ch << 5));
#pragma unroll
          for (int i = 0; i < 4; ++i) q[t][i] = ldsc(p + i);
        }
#pragma unroll
        for (int t = 0; t < 4; ++t) {
          s8v bh, bl; unpack8(q[t], bh, bl);
          acc0[t] = MFMA(a0h[ch], bh, acc0[t]);
          acc1[t] = MFMA(a1h[ch], bh, acc1[t]);
          acc0[t] = MFMA(a0l[ch], bh, acc0[t]);
          acc1[t] = MFMA(a1l[ch], bh, acc1[t]);
          acc0[t] = MFMA(a0h[ch], bl, acc0[t]);
          acc1[t] = MFMA(a1h[ch], bl, acc1[t]);
        }
      }
    }

    if (ss < TT) {
#pragma unroll
      for (int t = 0; t < 4; ++t)
#pragma unroll
        for (int r = 0; r < 4; ++r)
          zpf[r * 2080 + quad * 520 + (wv << 6) + t * 16 + n] = acc0[t][r];
      __syncthreads();
      if (tid < 256) {
        f4v s = tzv;
#pragma unroll
        for (int g = 0; g < 4; ++g) {
          float x = 0.f;
#pragma unroll
          for (int w = 0; w < 8; ++w) x += zpf[g * 2080 + j * 520 + (w << 6) + lane];
          s[g] += x;
        }
        float iG = 1.f / (1.f + expf(-s.x));
        float fG = 1.f / (1.f + expf(-s.y));
        float gG = tanhf(s.z);
        float oG = 1.f / (1.f + expf(-s.w));
        c0 = fG * c0 + iG * gG;
        float h = oG * tanhf(c0);
        unsigned hb16 = (unsigned)f2bf(h);
        unsigned lo16 = (unsigned)f2bf(h - __uint_as_float(hb16 << 16));
        hx[lane * 5 + j] = (hb16 << 16) | lo16;
      }
      __syncthreads();
      if (wv == 7) {
        unsigned v0 = hx[lane * 5 + 0], v1 = hx[lane * 5 + 1];
        unsigned v2 = hx[lane * 5 + 2], v3 = hx[lane * 5 + 3];
        u64* p = (u64*)(h0w + s0w * HSZ + (lane << 10) + (wg << 2));
        stsc(p, (u64)v0 | ((u64)v1 << 32));
        stsc(p + 1, (u64)v2 | ((u64)v3 << 32));
        asm volatile("s_waitcnt vmcnt(0)" ::: "memory");
        if (lane == 0) arrive(xcA, gcA, genA, grp);
      }
    }

    // ---- wait_B: h1(ss-2) stores complete grid-wide ----
    if (bt && ss >= 1) waitgen(genB, (unsigned)(ss - 1));
    __syncthreads();

    // ======== h1 pass: acc1 += U1·h1(ss-2); layer-1 gates ========
    if (ss >= 1) {
      {
        const unsigned* hb = h1w + s1r * HSZ;
#pragma unroll
        for (int ch = 0; ch < 4; ++ch) {
          u64 q[4][4];
#pragma unroll
          for (int t = 0; t < 4; ++t) {
            const u64* p = (const u64*)(hb + ((t * 16 + n) << 10) + co + (ch << 5));
#pragma unroll
            for (int i = 0; i < 4; ++i) q[t][i] = ldsc(p + i);
          }
#pragma unroll
          for (int t = 0; t < 4; ++t) {
            s8v bh, bl; unpack8(q[t], bh, bl);
            acc1[t] = MFMA(a1h[4 + ch], bh, acc1[t]);
            acc1[t] = MFMA(a1l[4 + ch], bh, acc1[t]);
            acc1[t] = MFMA(a1h[4 + ch], bl, acc1[t]);
          }
        }
      }
#pragma unroll
      for (int t = 0; t < 4; ++t)
#pragma unroll
        for (int r = 0; r < 4; ++r)
          zpf[r * 2080 + quad * 520 + (wv << 6) + t * 16 + n] = acc1[t][r];
      __syncthreads();
      if (tid < 256) {
        f4v s = b1v;
#pragma unroll
        for (int g = 0; g < 4; ++g) {
          float x = 0.f;
#pragma unroll
          for (int w = 0; w < 8; ++w) x += zpf[g * 2080 + j * 520 + (w << 6) + lane];
          s[g] += x;
        }
        float iG = 1.f / (1.f + expf(-s.x));
        float fG = 1.f / (1.f + expf(-s.y));
        float gG = tanhf(s.z);
        float oG = 1.f / (1.f + expf(-s.w));
        c1 = fG * c1 + iG * gG;
        hout = oG * tanhf(c1);
        unsigned hb16 = (unsigned)f2bf(hout);
        unsigned lo16 = (unsigned)f2bf(hout - __uint_as_float(hb16 << 16));
        hx[lane * 5 + j] = (hb16 << 16) | lo16;
      }
      __syncthreads();
      if (wv == 7) {
        unsigned v0 = hx[lane * 5 + 0], v1 = hx[lane * 5 + 1];
        unsigned v2 = hx[lane * 5 + 2], v3 = hx[lane * 5 + 3];
        u64* p = (u64*)(h1w + s1wr * HSZ + (lane << 10) + (wg << 2));
        stsc(p, (u64)v0 | ((u64)v1 << 32));
        stsc(p + 1, (u64)v2 | ((u64)v3 << 32));
        asm volatile("s_waitcnt vmcnt(0)" ::: "memory");
        if (lane == 0) arrive(xcB, gcB, genB, grp);
      }
      // out store: plain/cached, drained by a later waitcnt or kernel end
      if (tid < 256)
        out[(size_t)lane * (TT * UU) + (size_t)(ss - 1) * UU + (wg << 2) + j] = hout;
    }
  }
}

// ---------------- host ----------------
extern "C" void kernel_launch(void* const* d_in, const int* in_sizes, int n_in,
                              void* d_out, int out_size, void* d_ws, size_t ws_size,
                              hipStream_t stream) {
  const int*   tokens = (const int*)d_in[0];
  const float* embed  = (const float*)d_in[1];
  const float* W0     = (const float*)d_in[2];
  const float* U0     = (const float*)d_in[3];
  const float* b0     = (const float*)d_in[4];
  const float* W1     = (const float*)d_in[5];
  const float* U1     = (const float*)d_in[6];
  const float* b1     = (const float*)d_in[7];
  char* ws = (char*)d_ws;
  float*          tz  = (float*)(ws + B_TZ);
  unsigned short* A0h = (unsigned short*)(ws + B_A0H);
  unsigned short* A0l = (unsigned short*)(ws + B_A0L);
  unsigned short* A1h = (unsigned short*)(ws + B_A1H);
  unsigned short* A1l = (unsigned short*)(ws + B_A1L);
  unsigned*       h0w = (unsigned*)(ws + B_H0);
  unsigned*       h1w = (unsigned*)(ws + B_H1);
  unsigned*       bar = (unsigned*)(ws + B_BAR);
  float* out = (float*)d_out;

  // zero h slots + barrier block (ws poisoned 0xAA before every call)
  hipMemsetAsync(ws + B_H0, 0, (size_t)(6ull * HSZ * 4ull + 4096ull), stream);

  pack_a0_k<<<16384, 256, 0, stream>>>(U0, A0h, A0l);
  pack_a1_k<<<32768, 256, 0, stream>>>(W1, U1, A1h, A1l);
  tz_gemm_k<<<dim3(64, 16), 256, 0, stream>>>(embed, W0, b0, tz);

  void* args[] = {(void*)&tokens, (void*)&tz, (void*)&A0h, (void*)&A0l,
                  (void*)&A1h, (void*)&A1l, (void*)&b1, (void*)&h0w, (void*)&h1w,
                  (void*)&out, (void*)&bar};
  hipLaunchCooperativeKernel((void*)lstm_coop_k, dim3(256), dim3(512), args, 0, stream);
}